// Round 5
// baseline (160.116 us; speedup 1.0000x reference)
//
#include <hip/hip_runtime.h>

// GNN: 2x SAGEConv(sum) + global_add_pool + Linear head.
// N=50000 nodes, E=1e6 edges, D=H=64, G=512 graphs, O=16.
//
// R1: CSR gather replaced scatter atomics (2111 -> 606 us).
// R2: sorted-segment pooling replaced atomic pooling (606 -> 395 us).
// R3: binned counting sort for CSR build (395 -> 367 us).
// R4: bf16 feature storage, fp32 accumulate (367 -> 325 us).
// R5: bucket-local degree counting (325 -> 302 us).
// R6: scan-free CSR; grid-stride GEMM regressed (net wash).
// R7: MFMA GEMM, K=128 N=64 bf16 16x16x32 (305 -> 240 us).
// R8/R9: gather XCD experiments — full-machine 8x-dup gather is the floor.
// R10: LDS-presort scatter + pooling fused into GEMM-2 (240 -> 197 us).
// R11: gather fused into MFMA GEMM (197 -> 193).
// R12: full-line gather inside fused kernel REGRESSED (193 -> 207).
// R13: 2-wave cooperative fusion, trip=max8 (193 -> 182).
// R14: 2-way edge-split gather: only 182 -> 180.
// R15: dst>>8 buckets, bucket_sort fully LDS-staged (180 -> 173).
// R16: fp8-e4m3 gather operand (L2-resident table): only 173 -> 167.
// R17: 4-deep software pipeline of the gather (167 -> 157.5). Confirmed:
//      gather is exposed-dependent-latency bound; ILP is the lever.
// R18: col window staged in LDS + 8-deep fb pipeline. A block's 16 rows
//      are consecutive nodes in ONE bucket -> their col entries form a
//      single contiguous ~320-entry window. Coalesced-stage it into LDS
//      (cidx[1024], one barrier), so the gather's only global chain is
//      the independent fb stream: indices from LDS cost ~0 latency and
//      no vmcnt slot -> 8-deep named-register pipeline keeps ~2x the
//      feature loads in flight. Per-row fallback to the R17 global path
//      if the window exceeds 1024 (correctness guard; ~never fires).

namespace {
constexpr int NN = 50000;
constexpr int NE = 1000000;
constexpr int NG = 512;
constexpr int NO = 16;
constexpr int KB = 196;                     // buckets: dst>>8 (256 nodes)
constexpr int BCAP = 10240;                 // slot capacity per bucket
constexpr int EPT = 8;                      // edges per thread (scatter)
constexpr int EPB = 256 * EPT;              // 2048 edges per block
constexpr int SBLK = (NE + EPB - 1) / EPB;  // 489 scatter blocks
constexpr int SEDGE = BCAP;                 // full bucket staged (40 KB)
constexpr int CVT_BLK = (NN * 64 / 8 + 255) / 256;  // 1563 cvt blocks
constexpr int WP_BLK = 64;                  // weight-prep blocks
constexpr int CIDX_CAP = 1024;              // staged col window per block
}

typedef __attribute__((ext_vector_type(8))) short bf16x8;
typedef __attribute__((ext_vector_type(4))) float f32x4;
typedef __attribute__((ext_vector_type(2))) float f32x2;

__device__ __forceinline__ unsigned short f2bf(float f) {
  unsigned u = __float_as_uint(f);
  u += 0x7FFFu + ((u >> 16) & 1u);  // round-to-nearest-even
  return (unsigned short)(u >> 16);
}

__device__ __forceinline__ unsigned char f2fp8(float f) {
  return (unsigned char)(__builtin_amdgcn_cvt_pk_fp8_f32(f, f, 0, false) &
                         0xFF);
}

// ---------- prep: x->bf16+fp8 | weight transpose | bucket scatter ----------
__global__ __launch_bounds__(256) void prep_all(
    const float* __restrict__ x, unsigned short* __restrict__ x_bf,
    unsigned char* __restrict__ x_f8, const float* __restrict__ Wl1,
    const float* __restrict__ Wr1, const float* __restrict__ Wl2,
    const float* __restrict__ Wr2, unsigned short* __restrict__ Wt1,
    unsigned short* __restrict__ Wt2, const int* __restrict__ ei,
    int* __restrict__ bcount, unsigned int* __restrict__ ebuf) {
  __shared__ unsigned int stage[EPB];  // 8 KB (scatter role)
  __shared__ int cnt[256];
  __shared__ int lbase[256];
  __shared__ int cur[256];
  __shared__ int gbase[256];
  __shared__ int total_sh;
  int b = blockIdx.x;
  int t = threadIdx.x;

  if (b < CVT_BLK) {  // ---- x -> bf16 + fp8
    int i = b * 256 + t;
    if (i >= NN * 8) return;
    const float4* p = reinterpret_cast<const float4*>(x) + (size_t)i * 2;
    float4 a = p[0], bb = p[1];
    uint4 u;
    u.x = (unsigned)f2bf(a.x) | ((unsigned)f2bf(a.y) << 16);
    u.y = (unsigned)f2bf(a.z) | ((unsigned)f2bf(a.w) << 16);
    u.z = (unsigned)f2bf(bb.x) | ((unsigned)f2bf(bb.y) << 16);
    u.w = (unsigned)f2bf(bb.z) | ((unsigned)f2bf(bb.w) << 16);
    reinterpret_cast<uint4*>(x_bf)[i] = u;
    unsigned lo = __builtin_amdgcn_cvt_pk_fp8_f32(a.x, a.y, 0, false);
    lo = __builtin_amdgcn_cvt_pk_fp8_f32(a.z, a.w, lo, true);
    unsigned hi = __builtin_amdgcn_cvt_pk_fp8_f32(bb.x, bb.y, 0, false);
    hi = __builtin_amdgcn_cvt_pk_fp8_f32(bb.z, bb.w, hi, true);
    uint2 u8;
    u8.x = lo;
    u8.y = hi;
    reinterpret_cast<uint2*>(x_f8)[i] = u8;
    return;
  }
  if (b < CVT_BLK + WP_BLK) {  // ---- Wt[n][kk] transpose, both layers
    int id = (b - CVT_BLK) * 256 + t;  // 16384 total
    int half = id >> 13;
    int e = id & 8191;
    int nrow = e >> 7;
    int kk = e & 127;
    const float* Wl = half ? Wl2 : Wl1;
    const float* Wr = half ? Wr2 : Wr1;
    unsigned short* Wt = half ? Wt2 : Wt1;
    float v = (kk < 64) ? Wl[kk * 64 + nrow] : Wr[(kk - 64) * 64 + nrow];
    Wt[nrow * 128 + kk] = f2bf(v);
    return;
  }
  // ---- bucket scatter (LDS presort, coalesced run copy-out)
  int sb = b - (CVT_BLK + WP_BLK);
  cnt[t] = 0;
  __syncthreads();
  int e0 = sb * EPB;
  unsigned int pk[EPT];
#pragma unroll
  for (int i = 0; i < EPT; ++i) {
    int e = e0 + i * 256 + t;
    if (e < NE) {
      unsigned int src = (unsigned int)ei[e];
      unsigned int dst = (unsigned int)ei[NE + e];
      pk[i] = (dst << 16) | src;
      atomicAdd(&cnt[dst >> 8], 1);
    } else {
      pk[i] = 0xFFFFFFFFu;
    }
  }
  __syncthreads();
  int deg = cnt[t];
  for (int off = 1; off < 256; off <<= 1) {
    int u = (t >= off) ? cnt[t - off] : 0;
    __syncthreads();
    cnt[t] += u;
    __syncthreads();
  }
  {
    int excl = cnt[t] - deg;
    lbase[t] = excl;
    cur[t] = excl;
    if (t < KB) gbase[t] = t * BCAP + atomicAdd(&bcount[t], deg);
    if (t == 255) total_sh = cnt[255];
  }
  __syncthreads();
#pragma unroll
  for (int i = 0; i < EPT; ++i) {
    if (pk[i] != 0xFFFFFFFFu) {
      int bb2 = pk[i] >> 24;  // dst >> 8
      int s = atomicAdd(&cur[bb2], 1);
      stage[s] = pk[i];
    }
  }
  __syncthreads();
  int total = total_sh;
  for (int s = t; s < total; s += 256) {
    unsigned int p = stage[s];
    int bb2 = p >> 24;
    ebuf[gbase[bb2] + (s - lbase[bb2])] = p;
  }
}

// One 512-thread block per bucket (196 blocks): full bucket staged in
// LDS, hist + scan over 256 in-bucket nodes, place into col (ushort),
// emit meta[node] = (col_beg << 11) | deg.
__global__ __launch_bounds__(512) void bucket_sort(
    const unsigned int* __restrict__ ebuf, const int* __restrict__ bcount,
    unsigned int* __restrict__ meta, unsigned short* __restrict__ col) {
  __shared__ unsigned int se[SEDGE];  // 40 KB edge stage (covers BCAP)
  __shared__ int cnt[256];
  __shared__ int cur[256];
  int b = blockIdx.x;
  int t = threadIdx.x;
  int n = bcount[b];
  const unsigned int* eb = ebuf + (size_t)b * BCAP;
  if (t < 256) cnt[t] = 0;
  __syncthreads();
  for (int j = t; j < n; j += 512) {
    unsigned int p = eb[j];
    se[j] = p;
    atomicAdd(&cnt[(p >> 16) & 255], 1);
  }
  __syncthreads();
  int deg = (t < 256) ? cnt[t] : 0;
  for (int off = 1; off < 256; off <<= 1) {
    int u = (t >= off && t < 256) ? cnt[t - off] : 0;
    __syncthreads();
    if (t < 256) cnt[t] += u;
    __syncthreads();
  }
  if (t < 256) {
    int excl = cnt[t] - deg;
    cur[t] = excl;
    int node = (b << 8) + t;
    if (node < NN) {
      meta[node] = ((unsigned)(b * BCAP + excl) << 11) | (unsigned)deg;
    }
  }
  __syncthreads();
  unsigned short* cb = col + (size_t)b * BCAP;
  for (int j = t; j < n; j += 512) {
    unsigned int p = se[j];
    int d = (p >> 16) & 255;
    int pos = atomicAdd(&cur[d], 1);
    cb[pos] = (unsigned short)(p & 0xFFFFu);
  }
}

// ---------- fused gather(fp8) + MFMA GEMM, LDS-col + 8-deep pipeline -------
// Block = 4 waves = 16 rows (3125 blocks, exact tiling of N=50000).
// Phase 0: block's contiguous col window (~320 entries) coalesced into
// LDS cidx[]. Phase 1 (gather): row r, parity half h, chunk o; indices
// come from LDS (no global chase), fb loads are a pure independent
// stream pipelined 8 deep in named registers (clamped tail, predicated
// accumulate). Halves combine via __shfl_xor(8); h==0 lanes pack bf16 ->
// LDS tile. Phase 2: wave wv computes one 16-col t-tile (4 MFMAs); root
// term (bf16) + bias preloaded before the barriers.
// POOL=false: epilogue writes h1 as bf16 AND fp8. POOL=true: relu->psm,
// barrier, 64 column walkers do the sorted-batch segment walk.
template <bool POOL>
__global__ __launch_bounds__(256) void sage_fused(
    const unsigned short* __restrict__ feat,   // bf16 (root term)
    const unsigned char* __restrict__ feat8,   // fp8 (gather operand)
    const unsigned int* __restrict__ meta, const unsigned short* __restrict__ col,
    const unsigned short* __restrict__ Wt, const float* __restrict__ bias,
    unsigned short* __restrict__ out, unsigned char* __restrict__ out8,
    const int* __restrict__ batch, float* __restrict__ pooled) {
  __shared__ __align__(16) unsigned short tile[16][72];  // 2.3 KB
  __shared__ float psm[16][64];                          // 4 KB (POOL)
  __shared__ unsigned short cidx[CIDX_CAP];              // 2 KB col window
  int tid = threadIdx.x;
  int wave = tid >> 6;
  int lane = tid & 63;
  long base = (long)blockIdx.x * 16;  // exact: no row tail anywhere

  // gather lane roles (meta heads the dependent chain -> issue first)
  int r = lane >> 4;        // row-in-wave 0..3
  int h = (lane >> 3) & 1;  // edge parity half
  int o = lane & 7;         // 8B chunk
  long row = base + wave * 4 + r;
  unsigned int md = meta[row];
  unsigned int md0 = meta[base];
  unsigned int mdF = meta[base + 15];

  // MFMA-phase lane roles + independent preloads (hide under gather)
  int m = lane & 15;
  int q = lane >> 4;
  const unsigned short* hrow = feat + (base + m) * 64;
  bf16x8 af2 = *(const bf16x8*)(hrow + q * 8);       // k 64..95
  bf16x8 af3 = *(const bf16x8*)(hrow + 32 + q * 8);  // k 96..127
  float bv = bias[wave * 16 + m];

  // ---- phase 0: stage the block's col window into LDS (coalesced)
  int cbeg = (int)(md0 >> 11);
  int cend = (int)(mdF >> 11) + (int)(mdF & 2047u);
  int L = cend - cbeg;
  for (int j = tid; j < L && j < CIDX_CAP; j += 256) cidx[j] = col[cbeg + j];
  __syncthreads();

  // ---- phase 1: gather, 8-deep fb pipeline, indices from LDS
  {
    int beg = (int)(md >> 11);
    int deg = (int)(md & 2047u);
    int T = (deg - h + 1) >> 1;  // # edges of parity h (0 if deg<=h)
    const uint2* fb = reinterpret_cast<const uint2*>(feat8);
    float a0 = 0.f, a1 = 0.f, a2 = 0.f, a3 = 0.f;
    float a4 = 0.f, a5 = 0.f, a6 = 0.f, a7 = 0.f;

    auto ACC = [&](uint2 u) {
      f32x2 l0 = __builtin_amdgcn_cvt_pk_f32_fp8(u.x, false);
      f32x2 l1 = __builtin_amdgcn_cvt_pk_f32_fp8(u.x, true);
      f32x2 l2 = __builtin_amdgcn_cvt_pk_f32_fp8(u.y, false);
      f32x2 l3 = __builtin_amdgcn_cvt_pk_f32_fp8(u.y, true);
      a0 += l0.x;
      a1 += l0.y;
      a2 += l1.x;
      a3 += l1.y;
      a4 += l2.x;
      a5 += l2.y;
      a6 += l3.x;
      a7 += l3.y;
    };

    if (beg - cbeg + deg <= CIDX_CAP) {
      // ---- LDS-index path (normal): pure fb stream, 8 deep
      const unsigned short* cpl = &cidx[(beg - cbeg) + h];  // stride-2 walk
      int s0 = cpl[0];
      int s1 = cpl[(1 < T ? 1 : 0) * 2];
      int s2 = cpl[(2 < T ? 2 : 0) * 2];
      int s3 = cpl[(3 < T ? 3 : 0) * 2];
      int s4 = cpl[(4 < T ? 4 : 0) * 2];
      int s5 = cpl[(5 < T ? 5 : 0) * 2];
      int s6 = cpl[(6 < T ? 6 : 0) * 2];
      int s7 = cpl[(7 < T ? 7 : 0) * 2];
      uint2 u0 = fb[(size_t)s0 * 8 + o];
      uint2 u1 = fb[(size_t)s1 * 8 + o];
      uint2 u2 = fb[(size_t)s2 * 8 + o];
      uint2 u3 = fb[(size_t)s3 * 8 + o];
      uint2 u4 = fb[(size_t)s4 * 8 + o];
      uint2 u5 = fb[(size_t)s5 * 8 + o];
      uint2 u6 = fb[(size_t)s6 * 8 + o];
      uint2 u7 = fb[(size_t)s7 * 8 + o];
      for (int k = 0; k < T; k += 8) {
        int t0 = cpl[((k + 8 < T) ? (k + 8) : 0) * 2];
        int t1 = cpl[((k + 9 < T) ? (k + 9) : 0) * 2];
        int t2 = cpl[((k + 10 < T) ? (k + 10) : 0) * 2];
        int t3 = cpl[((k + 11 < T) ? (k + 11) : 0) * 2];
        int t4 = cpl[((k + 12 < T) ? (k + 12) : 0) * 2];
        int t5 = cpl[((k + 13 < T) ? (k + 13) : 0) * 2];
        int t6 = cpl[((k + 14 < T) ? (k + 14) : 0) * 2];
        int t7 = cpl[((k + 15 < T) ? (k + 15) : 0) * 2];
        uint2 v0 = fb[(size_t)t0 * 8 + o];
        uint2 v1 = fb[(size_t)t1 * 8 + o];
        uint2 v2 = fb[(size_t)t2 * 8 + o];
        uint2 v3 = fb[(size_t)t3 * 8 + o];
        uint2 v4 = fb[(size_t)t4 * 8 + o];
        uint2 v5 = fb[(size_t)t5 * 8 + o];
        uint2 v6 = fb[(size_t)t6 * 8 + o];
        uint2 v7 = fb[(size_t)t7 * 8 + o];
        ACC(u0);  // k+0 < T guaranteed by loop condition
        if (k + 1 < T) ACC(u1);
        if (k + 2 < T) ACC(u2);
        if (k + 3 < T) ACC(u3);
        if (k + 4 < T) ACC(u4);
        if (k + 5 < T) ACC(u5);
        if (k + 6 < T) ACC(u6);
        if (k + 7 < T) ACC(u7);
        u0 = v0;
        u1 = v1;
        u2 = v2;
        u3 = v3;
        u4 = v4;
        u5 = v5;
        u6 = v6;
        u7 = v7;
      }
    } else {
      // ---- global-index fallback (window overflow; ~never fires)
      const unsigned short* cp = col + beg + h;
      int s0 = cp[0];
      int s1 = cp[(1 < T ? 1 : 0) * 2];
      int s2 = cp[(2 < T ? 2 : 0) * 2];
      int s3 = cp[(3 < T ? 3 : 0) * 2];
      uint2 u0 = fb[(size_t)s0 * 8 + o];
      uint2 u1 = fb[(size_t)s1 * 8 + o];
      uint2 u2 = fb[(size_t)s2 * 8 + o];
      uint2 u3 = fb[(size_t)s3 * 8 + o];
      for (int k = 0; k < T; k += 4) {
        int t0 = cp[((k + 4 < T) ? (k + 4) : 0) * 2];
        int t1 = cp[((k + 5 < T) ? (k + 5) : 0) * 2];
        int t2 = cp[((k + 6 < T) ? (k + 6) : 0) * 2];
        int t3 = cp[((k + 7 < T) ? (k + 7) : 0) * 2];
        uint2 v0 = fb[(size_t)t0 * 8 + o];
        uint2 v1 = fb[(size_t)t1 * 8 + o];
        uint2 v2 = fb[(size_t)t2 * 8 + o];
        uint2 v3 = fb[(size_t)t3 * 8 + o];
        ACC(u0);
        if (k + 1 < T) ACC(u1);
        if (k + 2 < T) ACC(u2);
        if (k + 3 < T) ACC(u3);
        u0 = v0;
        u1 = v1;
        u2 = v2;
        u3 = v3;
      }
    }

    // combine the two edge-parity halves (lanes differ by 8)
    a0 += __shfl_xor(a0, 8);
    a1 += __shfl_xor(a1, 8);
    a2 += __shfl_xor(a2, 8);
    a3 += __shfl_xor(a3, 8);
    a4 += __shfl_xor(a4, 8);
    a5 += __shfl_xor(a5, 8);
    a6 += __shfl_xor(a6, 8);
    a7 += __shfl_xor(a7, 8);
    if (h == 0) {
      uint4 pk;
      pk.x = (unsigned)f2bf(a0) | ((unsigned)f2bf(a1) << 16);
      pk.y = (unsigned)f2bf(a2) | ((unsigned)f2bf(a3) << 16);
      pk.z = (unsigned)f2bf(a4) | ((unsigned)f2bf(a5) << 16);
      pk.w = (unsigned)f2bf(a6) | ((unsigned)f2bf(a7) << 16);
      *reinterpret_cast<uint4*>(&tile[wave * 4 + r][o * 8]) = pk;
    }
  }
  __syncthreads();

  // ---- phase 2: MFMA, wave wv computes t-tile = wv (one 16-col tile)
  bf16x8 af0 = *reinterpret_cast<const bf16x8*>(&tile[m][q * 8]);
  bf16x8 af1 = *reinterpret_cast<const bf16x8*>(&tile[m][32 + q * 8]);
  f32x4 acc;
  acc[0] = bv;
  acc[1] = bv;
  acc[2] = bv;
  acc[3] = bv;
  const unsigned short* wrow = Wt + (size_t)(wave * 16 + m) * 128 + q * 8;
  acc = __builtin_amdgcn_mfma_f32_16x16x32_bf16(
      af0, *(const bf16x8*)(wrow + 0), acc, 0, 0, 0);
  acc = __builtin_amdgcn_mfma_f32_16x16x32_bf16(
      af1, *(const bf16x8*)(wrow + 32), acc, 0, 0, 0);
  acc = __builtin_amdgcn_mfma_f32_16x16x32_bf16(
      af2, *(const bf16x8*)(wrow + 64), acc, 0, 0, 0);
  acc = __builtin_amdgcn_mfma_f32_16x16x32_bf16(
      af3, *(const bf16x8*)(wrow + 96), acc, 0, 0, 0);

  // ---- epilogue
  if (POOL) {
#pragma unroll
    for (int r2 = 0; r2 < 4; ++r2) {
      psm[q * 4 + r2][wave * 16 + m] = fmaxf(acc[r2], 0.f);
    }
    __syncthreads();
    if (tid < 64) {  // one walker per column
      int c = tid;
      float run = 0.f;
      int g = batch[base];
      for (int i = 0; i < 16; ++i) {
        int gi = batch[base + i];
        if (gi != g) {
          atomicAdd(&pooled[(size_t)g * 64 + c], run);
          run = 0.f;
          g = gi;
        }
        run += psm[i][c];
      }
      atomicAdd(&pooled[(size_t)g * 64 + c], run);
    }
  } else {
#pragma unroll
    for (int r2 = 0; r2 < 4; ++r2) {
      float v = fmaxf(acc[r2], 0.f);
      long rowc = base + q * 4 + r2;
      out[rowc * 64 + wave * 16 + m] = f2bf(v);
      out8[rowc * 64 + wave * 16 + m] = f2fp8(v);
    }
  }
}

// ---------------- head: out[g,o] = bo[o] + pooled[g,:] @ Wo[:,o] -----------
__global__ __launch_bounds__(256) void head_kernel(
    const float* __restrict__ pooled, const float* __restrict__ Wo,
    const float* __restrict__ bo, float* __restrict__ out) {
  int id = blockIdx.x * 256 + threadIdx.x;
  if (id >= NG * NO) return;
  int g = id >> 4, o = id & 15;
  float acc = bo[o];
  const float* p = pooled + (size_t)g * 64;
#pragma unroll
  for (int k = 0; k < 64; ++k) acc += p[k] * Wo[k * 16 + o];
  out[id] = acc;
}

extern "C" void kernel_launch(void* const* d_in, const int* in_sizes, int n_in,
                              void* d_out, int out_size, void* d_ws,
                              size_t ws_size, hipStream_t stream) {
  const float* x = (const float*)d_in[0];
  const int* ei = (const int*)d_in[1];
  const int* batch = (const int*)d_in[2];
  const float* Wl1 = (const float*)d_in[3];
  const float* Wr1 = (const float*)d_in[4];
  const float* b1 = (const float*)d_in[5];
  const float* Wl2 = (const float*)d_in[6];
  const float* Wr2 = (const float*)d_in[7];
  const float* b2 = (const float*)d_in[8];
  const float* Wo = (const float*)d_in[9];
  const float* bo = (const float*)d_in[10];
  float* out = (float*)d_out;

  // Workspace (~33 MB):
  unsigned short* x_bf = (unsigned short*)d_ws;     // NN*64 bf16 (6.4 MB)
  unsigned short* h1_bf = x_bf + (size_t)NN * 64;   // NN*64 bf16 (6.4 MB)
  unsigned char* x_f8 = (unsigned char*)(h1_bf + (size_t)NN * 64);  // 3.2 MB
  unsigned char* h1_f8 = x_f8 + (size_t)NN * 64;                    // 3.2 MB
  unsigned short* col = (unsigned short*)(h1_f8 + (size_t)NN * 64);
  unsigned short* Wt1 = col + (size_t)KB * BCAP;    // 64*128 bf16
  unsigned short* Wt2 = Wt1 + 64 * 128;             // 64*128 bf16
  unsigned int* ebuf = (unsigned int*)(Wt2 + 64 * 128);  // KB*BCAP (8.0MB)
  unsigned int* meta = ebuf + (size_t)KB * BCAP;    // NN
  int* bcount = (int*)(meta + NN);                  // KB
  float* pooled = (float*)(bcount + KB);            // NG*64 (contig w/bcount)

  // one memset covers bcount + pooled (contiguous)
  hipMemsetAsync(bcount, 0, KB * sizeof(int) + (size_t)NG * 64 * sizeof(float),
                 stream);

  const int fused_blocks = NN / 16;  // 3125, exact

  // prep: x->bf16+fp8 | weight transpose | bucket scatter (one launch)
  prep_all<<<CVT_BLK + WP_BLK + SBLK, 256, 0, stream>>>(
      x, x_bf, x_f8, Wl1, Wr1, Wl2, Wr2, Wt1, Wt2, ei, bcount, ebuf);

  // CSR finalize (196 concurrent blocks, fully LDS-staged)
  bucket_sort<<<KB, 512, 0, stream>>>(ebuf, bcount, meta, col);

  // Layer 1: fused gather+GEMM, writes h1 (bf16 + fp8)
  sage_fused<false><<<fused_blocks, 256, 0, stream>>>(
      x_bf, x_f8, meta, col, Wt1, b1, h1_bf, h1_f8, batch, pooled);

  // Layer 2: fused gather+GEMM+pool (h2 never materialized)
  sage_fused<true><<<fused_blocks, 256, 0, stream>>>(
      h1_bf, h1_f8, meta, col, Wt2, b2, nullptr, nullptr, batch, pooled);

  // Head from pooled (128 KB)
  head_kernel<<<(NG * NO + 255) / 256, 256, 0, stream>>>(pooled, Wo, bo, out);
}

// Round 6
// 150.982 us; speedup vs baseline: 1.0605x; 1.0605x over previous
//
#include <hip/hip_runtime.h>

// GNN: 2x SAGEConv(sum) + global_add_pool + Linear head.
// N=50000 nodes, E=1e6 edges, D=H=64, G=512 graphs, O=16.
//
// R1: CSR gather replaced scatter atomics (2111 -> 606 us).
// R2: sorted-segment pooling replaced atomic pooling (606 -> 395 us).
// R3: binned counting sort for CSR build (395 -> 367 us).
// R4: bf16 feature storage, fp32 accumulate (367 -> 325 us).
// R5: bucket-local degree counting (325 -> 302 us).
// R6: scan-free CSR; grid-stride GEMM regressed (net wash).
// R7: MFMA GEMM, K=128 N=64 bf16 16x16x32 (305 -> 240 us).
// R8/R9: gather XCD experiments — full-machine 8x-dup gather is the floor.
// R10: LDS-presort scatter + pooling fused into GEMM-2 (240 -> 197 us).
// R11: gather fused into MFMA GEMM (197 -> 193).
// R12: full-line gather inside fused kernel REGRESSED (193 -> 207).
// R13: 2-wave cooperative fusion, trip=max8 (193 -> 182).
// R14: 2-way edge-split gather: only 182 -> 180.
// R15: dst>>8 buckets, bucket_sort fully LDS-staged (180 -> 173).
// R16: fp8-e4m3 gather operand (L2-resident table): only 173 -> 167.
// R17: 4-deep software pipeline of the gather (167 -> 157.5). Confirmed:
//      gather is exposed-dependent-latency bound; ILP is the lever.
// R18: LDS-staged col window + 8-deep pipeline REGRESSED (157.5 -> 160):
//      staging overhead > residual chase latency. Per-wave ILP exhausted.
//      REVERTED here.
// R19: bf16 feature tables dropped entirely. Since R16 the gather is fp8;
//      bf16 existed only for the root term. Root rows now read from the
//      same fp8 table (uint2 loads issued at kernel top, cvt deferred to
//      after the gather; fp8->bf16 is exact). Saves ~26 MB of traffic:
//      prep x_bf write, sage-1 x_bf read, h1_bf write, sage-2 h1_bf read;
//      sage-1 epilogue stores halve.

namespace {
constexpr int NN = 50000;
constexpr int NE = 1000000;
constexpr int NG = 512;
constexpr int NO = 16;
constexpr int KB = 196;                     // buckets: dst>>8 (256 nodes)
constexpr int BCAP = 10240;                 // slot capacity per bucket
constexpr int EPT = 8;                      // edges per thread (scatter)
constexpr int EPB = 256 * EPT;              // 2048 edges per block
constexpr int SBLK = (NE + EPB - 1) / EPB;  // 489 scatter blocks
constexpr int SEDGE = BCAP;                 // full bucket staged (40 KB)
constexpr int CVT_BLK = (NN * 64 / 8 + 255) / 256;  // 1563 cvt blocks
constexpr int WP_BLK = 64;                  // weight-prep blocks
}

typedef __attribute__((ext_vector_type(8))) short bf16x8;
typedef __attribute__((ext_vector_type(4))) float f32x4;
typedef __attribute__((ext_vector_type(2))) float f32x2;

__device__ __forceinline__ unsigned short f2bf(float f) {
  unsigned u = __float_as_uint(f);
  u += 0x7FFFu + ((u >> 16) & 1u);  // round-to-nearest-even
  return (unsigned short)(u >> 16);
}

__device__ __forceinline__ unsigned char f2fp8(float f) {
  return (unsigned char)(__builtin_amdgcn_cvt_pk_fp8_f32(f, f, 0, false) &
                         0xFF);
}

// fp8x8 (uint2) -> bf16x8; exact (bf16 mantissa/exp superset of e4m3)
__device__ __forceinline__ bf16x8 f8x8_to_bf16(uint2 u) {
  f32x2 l0 = __builtin_amdgcn_cvt_pk_f32_fp8(u.x, false);
  f32x2 l1 = __builtin_amdgcn_cvt_pk_f32_fp8(u.x, true);
  f32x2 l2 = __builtin_amdgcn_cvt_pk_f32_fp8(u.y, false);
  f32x2 l3 = __builtin_amdgcn_cvt_pk_f32_fp8(u.y, true);
  bf16x8 r;
  r[0] = (short)f2bf(l0.x);
  r[1] = (short)f2bf(l0.y);
  r[2] = (short)f2bf(l1.x);
  r[3] = (short)f2bf(l1.y);
  r[4] = (short)f2bf(l2.x);
  r[5] = (short)f2bf(l2.y);
  r[6] = (short)f2bf(l3.x);
  r[7] = (short)f2bf(l3.y);
  return r;
}

// ---------- prep: x->fp8 | weight transpose | bucket scatter ---------------
__global__ __launch_bounds__(256) void prep_all(
    const float* __restrict__ x, unsigned char* __restrict__ x_f8,
    const float* __restrict__ Wl1, const float* __restrict__ Wr1,
    const float* __restrict__ Wl2, const float* __restrict__ Wr2,
    unsigned short* __restrict__ Wt1, unsigned short* __restrict__ Wt2,
    const int* __restrict__ ei, int* __restrict__ bcount,
    unsigned int* __restrict__ ebuf) {
  __shared__ unsigned int stage[EPB];  // 8 KB (scatter role)
  __shared__ int cnt[256];
  __shared__ int lbase[256];
  __shared__ int cur[256];
  __shared__ int gbase[256];
  __shared__ int total_sh;
  int b = blockIdx.x;
  int t = threadIdx.x;

  if (b < CVT_BLK) {  // ---- x -> fp8
    int i = b * 256 + t;
    if (i >= NN * 8) return;
    const float4* p = reinterpret_cast<const float4*>(x) + (size_t)i * 2;
    float4 a = p[0], bb = p[1];
    unsigned lo = __builtin_amdgcn_cvt_pk_fp8_f32(a.x, a.y, 0, false);
    lo = __builtin_amdgcn_cvt_pk_fp8_f32(a.z, a.w, lo, true);
    unsigned hi = __builtin_amdgcn_cvt_pk_fp8_f32(bb.x, bb.y, 0, false);
    hi = __builtin_amdgcn_cvt_pk_fp8_f32(bb.z, bb.w, hi, true);
    uint2 u8;
    u8.x = lo;
    u8.y = hi;
    reinterpret_cast<uint2*>(x_f8)[i] = u8;
    return;
  }
  if (b < CVT_BLK + WP_BLK) {  // ---- Wt[n][kk] transpose, both layers
    int id = (b - CVT_BLK) * 256 + t;  // 16384 total
    int half = id >> 13;
    int e = id & 8191;
    int nrow = e >> 7;
    int kk = e & 127;
    const float* Wl = half ? Wl2 : Wl1;
    const float* Wr = half ? Wr2 : Wr1;
    unsigned short* Wt = half ? Wt2 : Wt1;
    float v = (kk < 64) ? Wl[kk * 64 + nrow] : Wr[(kk - 64) * 64 + nrow];
    Wt[nrow * 128 + kk] = f2bf(v);
    return;
  }
  // ---- bucket scatter (LDS presort, coalesced run copy-out)
  int sb = b - (CVT_BLK + WP_BLK);
  cnt[t] = 0;
  __syncthreads();
  int e0 = sb * EPB;
  unsigned int pk[EPT];
#pragma unroll
  for (int i = 0; i < EPT; ++i) {
    int e = e0 + i * 256 + t;
    if (e < NE) {
      unsigned int src = (unsigned int)ei[e];
      unsigned int dst = (unsigned int)ei[NE + e];
      pk[i] = (dst << 16) | src;
      atomicAdd(&cnt[dst >> 8], 1);
    } else {
      pk[i] = 0xFFFFFFFFu;
    }
  }
  __syncthreads();
  int deg = cnt[t];
  for (int off = 1; off < 256; off <<= 1) {
    int u = (t >= off) ? cnt[t - off] : 0;
    __syncthreads();
    cnt[t] += u;
    __syncthreads();
  }
  {
    int excl = cnt[t] - deg;
    lbase[t] = excl;
    cur[t] = excl;
    if (t < KB) gbase[t] = t * BCAP + atomicAdd(&bcount[t], deg);
    if (t == 255) total_sh = cnt[255];
  }
  __syncthreads();
#pragma unroll
  for (int i = 0; i < EPT; ++i) {
    if (pk[i] != 0xFFFFFFFFu) {
      int bb2 = pk[i] >> 24;  // dst >> 8
      int s = atomicAdd(&cur[bb2], 1);
      stage[s] = pk[i];
    }
  }
  __syncthreads();
  int total = total_sh;
  for (int s = t; s < total; s += 256) {
    unsigned int p = stage[s];
    int bb2 = p >> 24;
    ebuf[gbase[bb2] + (s - lbase[bb2])] = p;
  }
}

// One 512-thread block per bucket (196 blocks): full bucket staged in
// LDS, hist + scan over 256 in-bucket nodes, place into col (ushort),
// emit meta[node] = (col_beg << 11) | deg.
__global__ __launch_bounds__(512) void bucket_sort(
    const unsigned int* __restrict__ ebuf, const int* __restrict__ bcount,
    unsigned int* __restrict__ meta, unsigned short* __restrict__ col) {
  __shared__ unsigned int se[SEDGE];  // 40 KB edge stage (covers BCAP)
  __shared__ int cnt[256];
  __shared__ int cur[256];
  int b = blockIdx.x;
  int t = threadIdx.x;
  int n = bcount[b];
  const unsigned int* eb = ebuf + (size_t)b * BCAP;
  if (t < 256) cnt[t] = 0;
  __syncthreads();
  for (int j = t; j < n; j += 512) {
    unsigned int p = eb[j];
    se[j] = p;
    atomicAdd(&cnt[(p >> 16) & 255], 1);
  }
  __syncthreads();
  int deg = (t < 256) ? cnt[t] : 0;
  for (int off = 1; off < 256; off <<= 1) {
    int u = (t >= off && t < 256) ? cnt[t - off] : 0;
    __syncthreads();
    if (t < 256) cnt[t] += u;
    __syncthreads();
  }
  if (t < 256) {
    int excl = cnt[t] - deg;
    cur[t] = excl;
    int node = (b << 8) + t;
    if (node < NN) {
      meta[node] = ((unsigned)(b * BCAP + excl) << 11) | (unsigned)deg;
    }
  }
  __syncthreads();
  unsigned short* cb = col + (size_t)b * BCAP;
  for (int j = t; j < n; j += 512) {
    unsigned int p = se[j];
    int d = (p >> 16) & 255;
    int pos = atomicAdd(&cur[d], 1);
    cb[pos] = (unsigned short)(p & 0xFFFFu);
  }
}

// ---------- fused gather(fp8) + MFMA GEMM, pipelined edge-split gather -----
// Block = 4 waves = 16 rows (3125 blocks, exact tiling of N=50000).
// GATHER (R17 structure): each wave covers 4 rows; per row, 16 lanes =
// 2 edge-parity halves x 8 chunks of 8 B. 4-deep software pipeline:
// prefetch col+fb for trips k+4..k+7 (named regs, index-clamped) before
// consuming trips k..k+3 (predicated fp32 accumulate via
// v_cvt_pk_f32_fp8). Halves combine via __shfl_xor(8); h==0 lanes pack
// bf16 -> LDS tile. One barrier; wave wv computes one 16-col t-tile
// (4 MFMAs). Root term read as fp8 uint2 at kernel top (latency spans
// the gather), converted to bf16 after the gather (exact). Bias
// preloaded early.
// POOL=false: epilogue writes h1 as fp8 only. POOL=true: relu->psm,
// barrier, 64 column walkers do the sorted-batch segment walk.
template <bool POOL>
__global__ __launch_bounds__(256) void sage_fused(
    const unsigned char* __restrict__ feat8,   // fp8 (gather + root)
    const unsigned int* __restrict__ meta, const unsigned short* __restrict__ col,
    const unsigned short* __restrict__ Wt, const float* __restrict__ bias,
    unsigned char* __restrict__ out8, const int* __restrict__ batch,
    float* __restrict__ pooled) {
  __shared__ __align__(16) unsigned short tile[16][72];  // 2.3 KB
  __shared__ float psm[16][64];                          // 4 KB (POOL)
  int tid = threadIdx.x;
  int wave = tid >> 6;
  int lane = tid & 63;
  long base = (long)blockIdx.x * 16;  // exact: no row tail anywhere

  // gather lane roles (meta heads the dependent chain -> issue first)
  int r = lane >> 4;        // row-in-wave 0..3
  int h = (lane >> 3) & 1;  // edge parity half
  int o = lane & 7;         // 8B chunk
  long row = base + wave * 4 + r;
  unsigned int md = meta[row];  // FIRST load issued

  // MFMA-phase lane roles + independent root-row preloads (fp8; the
  // loads' latency spans the whole gather, cvt happens after it)
  int m = lane & 15;
  int q = lane >> 4;
  const uint2* f8b = reinterpret_cast<const uint2*>(feat8);
  uint2 rt0 = f8b[(base + m) * 8 + q];      // root k 0..31 slice (af2)
  uint2 rt1 = f8b[(base + m) * 8 + 4 + q];  // root k 32..63 slice (af3)
  float bv = bias[wave * 16 + m];

  // ---- gather phase: 4-deep pipelined, 2-way edge split, fp8 source
  {
    int beg = (int)(md >> 11);
    int deg = (int)(md & 2047u);
    int T = (deg - h + 1) >> 1;  // # edges of parity h (0 if deg<=h)
    const uint2* fb = f8b;
    const unsigned short* cp = col + beg + h;  // stride-2 walk
    float a0 = 0.f, a1 = 0.f, a2 = 0.f, a3 = 0.f;
    float a4 = 0.f, a5 = 0.f, a6 = 0.f, a7 = 0.f;

    auto ACC = [&](uint2 u) {
      f32x2 l0 = __builtin_amdgcn_cvt_pk_f32_fp8(u.x, false);
      f32x2 l1 = __builtin_amdgcn_cvt_pk_f32_fp8(u.x, true);
      f32x2 l2 = __builtin_amdgcn_cvt_pk_f32_fp8(u.y, false);
      f32x2 l3 = __builtin_amdgcn_cvt_pk_f32_fp8(u.y, true);
      a0 += l0.x;
      a1 += l0.y;
      a2 += l1.x;
      a3 += l1.y;
      a4 += l2.x;
      a5 += l2.y;
      a6 += l3.x;
      a7 += l3.y;
    };

    // prologue: prefetch trips 0..3 (index-clamped; garbage stays in
    // workspace and is predicated out of the accumulate)
    int s0 = cp[0];
    int s1 = cp[(1 < T ? 1 : 0) * 2];
    int s2 = cp[(2 < T ? 2 : 0) * 2];
    int s3 = cp[(3 < T ? 3 : 0) * 2];
    uint2 u0 = fb[(size_t)s0 * 8 + o];
    uint2 u1 = fb[(size_t)s1 * 8 + o];
    uint2 u2 = fb[(size_t)s2 * 8 + o];
    uint2 u3 = fb[(size_t)s3 * 8 + o];

    for (int k = 0; k < T; k += 4) {
      // prefetch trips k+4..k+7 before consuming k..k+3
      int i4 = (k + 4 < T) ? (k + 4) : 0;
      int i5 = (k + 5 < T) ? (k + 5) : 0;
      int i6 = (k + 6 < T) ? (k + 6) : 0;
      int i7 = (k + 7 < T) ? (k + 7) : 0;
      int t0 = cp[i4 * 2];
      int t1 = cp[i5 * 2];
      int t2 = cp[i6 * 2];
      int t3 = cp[i7 * 2];
      uint2 v0 = fb[(size_t)t0 * 8 + o];
      uint2 v1 = fb[(size_t)t1 * 8 + o];
      uint2 v2 = fb[(size_t)t2 * 8 + o];
      uint2 v3 = fb[(size_t)t3 * 8 + o];
      ACC(u0);  // k+0 < T guaranteed by loop condition
      if (k + 1 < T) ACC(u1);
      if (k + 2 < T) ACC(u2);
      if (k + 3 < T) ACC(u3);
      u0 = v0;
      u1 = v1;
      u2 = v2;
      u3 = v3;
    }

    // combine the two edge-parity halves (lanes differ by 8)
    a0 += __shfl_xor(a0, 8);
    a1 += __shfl_xor(a1, 8);
    a2 += __shfl_xor(a2, 8);
    a3 += __shfl_xor(a3, 8);
    a4 += __shfl_xor(a4, 8);
    a5 += __shfl_xor(a5, 8);
    a6 += __shfl_xor(a6, 8);
    a7 += __shfl_xor(a7, 8);
    if (h == 0) {
      uint4 pk;
      pk.x = (unsigned)f2bf(a0) | ((unsigned)f2bf(a1) << 16);
      pk.y = (unsigned)f2bf(a2) | ((unsigned)f2bf(a3) << 16);
      pk.z = (unsigned)f2bf(a4) | ((unsigned)f2bf(a5) << 16);
      pk.w = (unsigned)f2bf(a6) | ((unsigned)f2bf(a7) << 16);
      *reinterpret_cast<uint4*>(&tile[wave * 4 + r][o * 8]) = pk;
    }
  }

  // root-term cvt (loads completed long ago; pure VALU, pre-barrier)
  bf16x8 af2 = f8x8_to_bf16(rt0);
  bf16x8 af3 = f8x8_to_bf16(rt1);
  __syncthreads();

  // ---- MFMA phase: wave wv computes t-tile = wv (one 16-col tile)
  bf16x8 af0 = *reinterpret_cast<const bf16x8*>(&tile[m][q * 8]);
  bf16x8 af1 = *reinterpret_cast<const bf16x8*>(&tile[m][32 + q * 8]);
  f32x4 acc;
  acc[0] = bv;
  acc[1] = bv;
  acc[2] = bv;
  acc[3] = bv;
  const unsigned short* wrow = Wt + (size_t)(wave * 16 + m) * 128 + q * 8;
  acc = __builtin_amdgcn_mfma_f32_16x16x32_bf16(
      af0, *(const bf16x8*)(wrow + 0), acc, 0, 0, 0);
  acc = __builtin_amdgcn_mfma_f32_16x16x32_bf16(
      af1, *(const bf16x8*)(wrow + 32), acc, 0, 0, 0);
  acc = __builtin_amdgcn_mfma_f32_16x16x32_bf16(
      af2, *(const bf16x8*)(wrow + 64), acc, 0, 0, 0);
  acc = __builtin_amdgcn_mfma_f32_16x16x32_bf16(
      af3, *(const bf16x8*)(wrow + 96), acc, 0, 0, 0);

  // ---- epilogue
  if (POOL) {
#pragma unroll
    for (int r2 = 0; r2 < 4; ++r2) {
      psm[q * 4 + r2][wave * 16 + m] = fmaxf(acc[r2], 0.f);
    }
    __syncthreads();
    if (tid < 64) {  // one walker per column
      int c = tid;
      float run = 0.f;
      int g = batch[base];
      for (int i = 0; i < 16; ++i) {
        int gi = batch[base + i];
        if (gi != g) {
          atomicAdd(&pooled[(size_t)g * 64 + c], run);
          run = 0.f;
          g = gi;
        }
        run += psm[i][c];
      }
      atomicAdd(&pooled[(size_t)g * 64 + c], run);
    }
  } else {
#pragma unroll
    for (int r2 = 0; r2 < 4; ++r2) {
      float v = fmaxf(acc[r2], 0.f);
      long rowc = base + q * 4 + r2;
      out8[rowc * 64 + wave * 16 + m] = f2fp8(v);
    }
  }
}

// ---------------- head: out[g,o] = bo[o] + pooled[g,:] @ Wo[:,o] -----------
__global__ __launch_bounds__(256) void head_kernel(
    const float* __restrict__ pooled, const float* __restrict__ Wo,
    const float* __restrict__ bo, float* __restrict__ out) {
  int id = blockIdx.x * 256 + threadIdx.x;
  if (id >= NG * NO) return;
  int g = id >> 4, o = id & 15;
  float acc = bo[o];
  const float* p = pooled + (size_t)g * 64;
#pragma unroll
  for (int k = 0; k < 64; ++k) acc += p[k] * Wo[k * 16 + o];
  out[id] = acc;
}

extern "C" void kernel_launch(void* const* d_in, const int* in_sizes, int n_in,
                              void* d_out, int out_size, void* d_ws,
                              size_t ws_size, hipStream_t stream) {
  const float* x = (const float*)d_in[0];
  const int* ei = (const int*)d_in[1];
  const int* batch = (const int*)d_in[2];
  const float* Wl1 = (const float*)d_in[3];
  const float* Wr1 = (const float*)d_in[4];
  const float* b1 = (const float*)d_in[5];
  const float* Wl2 = (const float*)d_in[6];
  const float* Wr2 = (const float*)d_in[7];
  const float* b2 = (const float*)d_in[8];
  const float* Wo = (const float*)d_in[9];
  const float* bo = (const float*)d_in[10];
  float* out = (float*)d_out;

  // Workspace (~20 MB):
  unsigned char* x_f8 = (unsigned char*)d_ws;        // NN*64 fp8 (3.2 MB)
  unsigned char* h1_f8 = x_f8 + (size_t)NN * 64;     // NN*64 fp8 (3.2 MB)
  unsigned short* col = (unsigned short*)(h1_f8 + (size_t)NN * 64);  // 4.0MB
  unsigned short* Wt1 = col + (size_t)KB * BCAP;     // 64*128 bf16
  unsigned short* Wt2 = Wt1 + 64 * 128;              // 64*128 bf16
  unsigned int* ebuf = (unsigned int*)(Wt2 + 64 * 128);  // KB*BCAP (8.0MB)
  unsigned int* meta = ebuf + (size_t)KB * BCAP;     // NN
  int* bcount = (int*)(meta + NN);                   // KB
  float* pooled = (float*)(bcount + KB);             // NG*64 (contig w/bcount)

  // one memset covers bcount + pooled (contiguous)
  hipMemsetAsync(bcount, 0, KB * sizeof(int) + (size_t)NG * 64 * sizeof(float),
                 stream);

  const int fused_blocks = NN / 16;  // 3125, exact

  // prep: x->fp8 | weight transpose | bucket scatter (one launch)
  prep_all<<<CVT_BLK + WP_BLK + SBLK, 256, 0, stream>>>(
      x, x_f8, Wl1, Wr1, Wl2, Wr2, Wt1, Wt2, ei, bcount, ebuf);

  // CSR finalize (196 concurrent blocks, fully LDS-staged)
  bucket_sort<<<KB, 512, 0, stream>>>(ebuf, bcount, meta, col);

  // Layer 1: fused gather+GEMM, writes h1 (fp8 only)
  sage_fused<false><<<fused_blocks, 256, 0, stream>>>(
      x_f8, meta, col, Wt1, b1, h1_f8, batch, pooled);

  // Layer 2: fused gather+GEMM+pool (h2 never materialized)
  sage_fused<true><<<fused_blocks, 256, 0, stream>>>(
      h1_f8, meta, col, Wt2, b2, nullptr, batch, pooled);

  // Head from pooled (128 KB)
  head_kernel<<<(NG * NO + 255) / 256, 256, 0, stream>>>(pooled, Wo, bo, out);
}